// Round 12
// baseline (204.136 us; speedup 1.0000x reference)
//
#include <hip/hip_runtime.h>
#include <math.h>

#define NROWS  500000
#define NCHK   7813      // ceil(500000/64)
#define EPSV   1e-5f

typedef __bf16 bf16_t;
typedef __bf16 bf16x4 __attribute__((ext_vector_type(4)));
typedef __bf16 bf16x8 __attribute__((ext_vector_type(8)));
typedef float  f32x4  __attribute__((ext_vector_type(4)));

// ---- ws layout (byte offsets) ----
static const size_t GT_OFF   = 131072;   // gramTot 16384 f32 (64KB)
static const size_t WB_OFF   = 327680;   // W bf16 (32KB)
static const size_t BIAS_OFF = 360960;   // 128 f32
static const size_t CS_OFF   = 393216;   // colsum partials G*128 f32 (ends 655360)
static const size_t CS2_OFF  = 786432;   // colsum slice partials 8*128 f32
static const size_t GRAM_OFF = 1048576;  // gram partials G*16384 f32

// ============ Kernel 1: column sums + Gram partials (bf16 MFMA) =============
// Rounds 6-11 structure, now with a 2-DEEP register pipeline: loads for chunk
// ch+2G issue a FULL iteration before their ds_write (counted-vmcnt window
// ~1500cy > ~900cy HBM latency; 1-deep window was only ~600cy of MFMAC).
__global__ __launch_bounds__(256) void k_stats(const float* __restrict__ X,
        float* __restrict__ csPart, float* __restrict__ gramPart) {
    __shared__ bf16_t sxtT[2][8192];    // [buf][f-major 128x64 swizzled] 32KB
    __shared__ float  scs[256][4];
    const int t    = threadIdx.x;
    const int lane = t & 63;
    const int w    = t >> 6;     // wave 0..3
    const int oct  = t >> 5;     // sample octet 0..7
    const int fg4  = t & 31;     // feature quad 0..31
    const int cl   = lane & 15;
    const int kq   = lane >> 4;
    const int G    = gridDim.x;

    f32x4 acc[2][8];
    #pragma unroll
    for (int a = 0; a < 2; a++)
        #pragma unroll
        for (int b = 0; b < 8; b++)
            acc[a][b] = (f32x4){0.f, 0.f, 0.f, 0.f};
    float cs0 = 0.f, cs1 = 0.f, cs2 = 0.f, cs3 = 0.f;

    f32x4 R0[8], R1[8];

    auto KF = [](int f) { return (f ^ (f >> 3)) & 7; };

    auto GLOADC = [&](int ch, f32x4 (&R)[8]) {
        const size_t row0 = (size_t)ch << 6;
        #pragma unroll
        for (int i = 0; i < 8; i++) {
            const size_t row = row0 + oct * 8 + i;
            R[i] = (row < NROWS)
                 ? *reinterpret_cast<const f32x4*>(X + row * 128 + fg4 * 4)
                 : (f32x4){0.f, 0.f, 0.f, 0.f};
        }
    };
    auto DSWRITEC = [&](int buf, const f32x4 (&R)[8]) {
        #pragma unroll
        for (int i = 0; i < 8; i++) {
            cs0 += R[i][0]; cs1 += R[i][1]; cs2 += R[i][2]; cs3 += R[i][3];
        }
        bf16_t* S = sxtT[buf];
        #pragma unroll
        for (int j = 0; j < 4; j++) {
            const int f = fg4 * 4 + j;
            const int g = oct ^ KF(f);
            bf16x8 v;
            #pragma unroll
            for (int i = 0; i < 8; i++) v[i] = (bf16_t)R[i][j];
            *reinterpret_cast<bf16x8*>(&S[f * 64 + g * 8]) = v;
        }
    };
    auto MFMAC = [&](int buf) {
        const bf16_t* S = sxtT[buf];
        #pragma unroll
        for (int kb = 0; kb < 2; kb++) {
            const int gq = kb * 4 + kq;            // sample-group index
            bf16x8 fa[2];
            #pragma unroll
            for (int a = 0; a < 2; a++) {
                const int f = (w * 2 + a) * 16 + cl;
                fa[a] = *reinterpret_cast<const bf16x8*>(&S[f * 64 + ((gq ^ KF(f)) << 3)]);
            }
            #pragma unroll
            for (int b = 0; b < 8; b++) {
                const int f = b * 16 + cl;
                const bf16x8 fb = *reinterpret_cast<const bf16x8*>(&S[f * 64 + ((gq ^ KF(f)) << 3)]);
                acc[0][b] = __builtin_amdgcn_mfma_f32_16x16x32_bf16(fa[0], fb, acc[0][b], 0, 0, 0);
                acc[1][b] = __builtin_amdgcn_mfma_f32_16x16x32_bf16(fa[1], fb, acc[1][b], 0, 0, 0);
            }
        }
    };

    int ch = blockIdx.x;                  // G <= 512 < NCHK: all blocks work
    GLOADC(ch, R0);
    if (ch + G < NCHK) GLOADC(ch + G, R1);
    DSWRITEC(0, R0);
    __syncthreads();
    // invariant at loop top: buf0 holds ch; R1 holds ch+G (if valid)
    for (;;) {
        const int c1 = ch + G;
        const bool v1 = c1 < NCHK;
        const int c2 = ch + 2 * G;
        const bool v2 = c2 < NCHK;
        if (v2) GLOADC(c2, R0);           // issue 1 full iteration early
        MFMAC(0);
        if (v1) DSWRITEC(1, R1);          // waits only R1's (old) loads
        __syncthreads();
        if (!v1) break;
        const int c3 = ch + 3 * G;
        if (c3 < NCHK) GLOADC(c3, R1);
        MFMAC(1);
        if (v2) DSWRITEC(0, R0);
        __syncthreads();
        if (!v2) break;
        ch = c2;
    }

    // Epilogue: transposed contiguous f32x4 nt stores (Gram^T == Gram).
    float* gp = gramPart + (size_t)blockIdx.x * 16384;
    #pragma unroll
    for (int a = 0; a < 2; a++)
        #pragma unroll
        for (int b = 0; b < 8; b++) {
            const int col  = b * 16 + cl;
            const int row0 = (w * 2 + a) * 16 + kq * 4;
            __builtin_nontemporal_store(acc[a][b],
                reinterpret_cast<f32x4*>(&gp[col * 128 + row0]));
        }
    scs[t][0] = cs0; scs[t][1] = cs1; scs[t][2] = cs2; scs[t][3] = cs3;
    __syncthreads();
    if (t < 128) {
        float s = 0.f;
        #pragma unroll
        for (int q = 0; q < 8; q++) s += scs[q * 32 + (t >> 2)][t & 3];
        csPart[(size_t)blockIdx.x * 128 + t] = s;
    }
}

// ============ Kernel 2: coalesced reduction -> gramTot + colsum slices ======
// Blocks 0..255: gram (round-8 structure, verified). Blocks 256..263: colsum
// slice s sums g in {s, s+8, ...} -> csPart2[s][128] (8 latency-bound iters,
// replacing the single mean block's 64 -> fixes the ~24us serial tail).
__global__ __launch_bounds__(256) void k_gred(const float* __restrict__ gramPart,
        const float* __restrict__ csPart, float* __restrict__ gramTot,
        float* __restrict__ csPart2, int G) {
    const int t = threadIdx.x;
    const int b = blockIdx.x;
    if (b >= 256) {                       // ---- colsum slice ----
        const int s = b - 256;
        if (t < 128) {
            float sum = 0.f;
            int g = s;
            for (; g + 56 < G; g += 64) {
                float p[8];
                #pragma unroll
                for (int u = 0; u < 8; u++)
                    p[u] = csPart[(size_t)(g + 8 * u) * 128 + t];
                sum += ((p[0] + p[1]) + (p[2] + p[3])) + ((p[4] + p[5]) + (p[6] + p[7]));
            }
            for (; g < G; g += 8) sum += csPart[(size_t)g * 128 + t];
            csPart2[s * 128 + t] = sum;
        }
        return;
    }
    const int e  = b * 64 + (t & 63);
    const int sl = t >> 6;                // g-slice 0..3
    float s = 0.f;
    int g = sl;
    for (; g + 28 < G; g += 32) {         // 8 loads of stride-4 per iter
        float v[8];
        #pragma unroll
        for (int u = 0; u < 8; u++)
            v[u] = __builtin_nontemporal_load(&gramPart[(size_t)(g + 4 * u) * 16384 + e]);
        s += ((v[0] + v[1]) + (v[2] + v[3])) + ((v[4] + v[5]) + (v[6] + v[7]));
    }
    for (; g < G; g += 4)
        s += __builtin_nontemporal_load(&gramPart[(size_t)g * 16384 + e]);
    __shared__ float red[4][64];
    red[sl][t & 63] = s;
    __syncthreads();
    if (t < 64)
        gramTot[b * 64 + t] = (red[0][t] + red[1][t]) + (red[2][t] + red[3][t]);
}

// ============ Kernel 3: fused Sigma->Sn, Newton-Schulz x5, W, bias ==========
// Round 9-11 core (verified). Phase 0 now folds the 8-slice colsum -> smean
// in LDS (1KB read), replacing the global mean[].
__global__ __launch_bounds__(256) void k_ns(const float* __restrict__ gramTot,
        const float* __restrict__ csPart2, const float* __restrict__ Rg,
        bf16_t* __restrict__ Wb, float* __restrict__ bias) {
    __shared__ bf16_t sPh[16384], sPl[16384], sSn[16384], sTT[16384];
    __shared__ float smean[128];
    const int t = threadIdx.x;
    const int w = t >> 6, lane = t & 63;
    const int cl = lane & 15, kq = lane >> 4;

    if (t < 128) {
        float m = 0.f;
        #pragma unroll
        for (int s = 0; s < 8; s++) m += csPart2[s * 128 + t];
        smean[t] = m * (1.0f / (float)NROWS);
    }
    __syncthreads();

    float* rs = reinterpret_cast<float*>(sTT);
    float dv = 0.f;
    if (t < 128) {
        const float m = smean[t];
        dv = gramTot[t * 129] * (1.0f / (float)NROWS) - m * m + EPSV;
    }
    rs[t] = dv;
    __syncthreads();
    #pragma unroll
    for (int off = 128; off > 0; off >>= 1) {
        if (t < off) rs[t] += rs[t + off];
        __syncthreads();
    }
    const float rTr = 1.0f / rs[0];
    __syncthreads();
    for (int i = 0; i < 64; i++) {
        const int e = t + (i << 8);
        const int r = e >> 7, c = e & 127;
        float s = gramTot[e] * (1.0f / (float)NROWS) - smean[r] * smean[c];
        if (r == c) s += EPSV;
        const int ix = r * 128 + (c ^ ((r & 7) << 3));
        const float snv = s * rTr;
        sSn[ix] = (bf16_t)snv;
        const float p0 = ((r == c) ? 1.5f : 0.f) - 0.5f * snv;
        const bf16_t ph = (bf16_t)p0;
        sPh[ix] = ph;
        sPl[ix] = (bf16_t)(p0 - (float)ph);
    }
    __syncthreads();

    f32x4 acc[2][8];
    auto NSMM = [&](const bf16_t* __restrict__ Bm) {
        #pragma unroll
        for (int a = 0; a < 2; a++)
            #pragma unroll
            for (int ct = 0; ct < 8; ct++) acc[a][ct] = (f32x4){0.f, 0.f, 0.f, 0.f};
        #pragma unroll
        for (int kb = 0; kb < 4; kb++) {
            const int k0 = kb * 32 + kq * 8;
            bf16x8 ah[2], al[2];
            #pragma unroll
            for (int a = 0; a < 2; a++) {
                const int ra = w * 32 + a * 16 + cl;
                const int ia = ra * 128 + (k0 ^ ((ra & 7) << 3));
                ah[a] = *reinterpret_cast<const bf16x8*>(&sPh[ia]);
                al[a] = *reinterpret_cast<const bf16x8*>(&sPl[ia]);
            }
            #pragma unroll
            for (int ct = 0; ct < 8; ct++) {
                const int rb = ct * 16 + cl;
                const bf16x8 bb = *reinterpret_cast<const bf16x8*>(
                    &Bm[rb * 128 + (k0 ^ ((rb & 7) << 3))]);
                acc[0][ct] = __builtin_amdgcn_mfma_f32_16x16x32_bf16(ah[0], bb, acc[0][ct], 0, 0, 0);
                acc[0][ct] = __builtin_amdgcn_mfma_f32_16x16x32_bf16(al[0], bb, acc[0][ct], 0, 0, 0);
                acc[1][ct] = __builtin_amdgcn_mfma_f32_16x16x32_bf16(ah[1], bb, acc[1][ct], 0, 0, 0);
                acc[1][ct] = __builtin_amdgcn_mfma_f32_16x16x32_bf16(al[1], bb, acc[1][ct], 0, 0, 0);
            }
        }
    };
    auto WRT = [&](bf16_t* __restrict__ D) {
        #pragma unroll
        for (int a = 0; a < 2; a++) {
            const int ro0 = w * 32 + a * 16 + kq * 4;
            #pragma unroll
            for (int ct = 0; ct < 8; ct++) {
                const int co = ct * 16 + cl;
                bf16x4 v = { (bf16_t)acc[a][ct][0], (bf16_t)acc[a][ct][1],
                             (bf16_t)acc[a][ct][2], (bf16_t)acc[a][ct][3] };
                *reinterpret_cast<bf16x4*>(&D[co * 128 + (ro0 ^ ((co & 7) << 3))]) = v;
            }
        }
    };

    for (int it = 0; it < 4; it++) {
        NSMM(sSn);
        WRT(sTT);
        __syncthreads();
        NSMM(sTT);
        __syncthreads();
        WRT(sTT);
        __syncthreads();
        NSMM(sTT);
        #pragma unroll
        for (int a = 0; a < 2; a++) {
            const int ro0 = w * 32 + a * 16 + kq * 4;
            #pragma unroll
            for (int ct = 0; ct < 8; ct++) {
                const int co = ct * 16 + cl;
                const int ix = co * 128 + (ro0 ^ ((co & 7) << 3));
                bf16x4 ph4 = *reinterpret_cast<const bf16x4*>(&sPh[ix]);
                bf16x4 pl4 = *reinterpret_cast<const bf16x4*>(&sPl[ix]);
                bf16x4 nh, nl;
                #pragma unroll
                for (int r = 0; r < 4; r++) {
                    const float pold = (float)ph4[r] + (float)pl4[r];
                    const float pn = 1.5f * pold - 0.5f * acc[a][ct][r];
                    nh[r] = (bf16_t)pn;
                    nl[r] = (bf16_t)(pn - (float)nh[r]);
                }
                *reinterpret_cast<bf16x4*>(&sPh[ix]) = nh;
                *reinterpret_cast<bf16x4*>(&sPl[ix]) = nl;
            }
        }
        __syncthreads();
    }

    const float scal = sqrtf(rTr);
    #pragma unroll
    for (int a = 0; a < 2; a++)
        #pragma unroll
        for (int ct = 0; ct < 8; ct++) acc[a][ct] = (f32x4){0.f, 0.f, 0.f, 0.f};
    #pragma unroll
    for (int kb = 0; kb < 4; kb++) {
        const int k0 = kb * 32 + kq * 8;
        bf16x8 ah[2], al[2];
        #pragma unroll
        for (int a = 0; a < 2; a++) {
            const int ra = w * 32 + a * 16 + cl;
            const float4 rv0 = *reinterpret_cast<const float4*>(&Rg[ra * 128 + k0]);
            const float4 rv1 = *reinterpret_cast<const float4*>(&Rg[ra * 128 + k0 + 4]);
            const float rv[8] = {rv0.x, rv0.y, rv0.z, rv0.w, rv1.x, rv1.y, rv1.z, rv1.w};
            bf16x8 h, l;
            #pragma unroll
            for (int j = 0; j < 8; j++) {
                h[j] = (bf16_t)rv[j];
                l[j] = (bf16_t)(rv[j] - (float)h[j]);
            }
            ah[a] = h; al[a] = l;
        }
        #pragma unroll
        for (int ct = 0; ct < 8; ct++) {
            const int rb = ct * 16 + cl;
            const int ib = rb * 128 + (k0 ^ ((rb & 7) << 3));
            const bf16x8 bh = *reinterpret_cast<const bf16x8*>(&sPh[ib]);
            const bf16x8 bl = *reinterpret_cast<const bf16x8*>(&sPl[ib]);
            #pragma unroll
            for (int a = 0; a < 2; a++) {
                acc[a][ct] = __builtin_amdgcn_mfma_f32_16x16x32_bf16(ah[a], bh, acc[a][ct], 0, 0, 0);
                acc[a][ct] = __builtin_amdgcn_mfma_f32_16x16x32_bf16(al[a], bh, acc[a][ct], 0, 0, 0);
                acc[a][ct] = __builtin_amdgcn_mfma_f32_16x16x32_bf16(ah[a], bl, acc[a][ct], 0, 0, 0);
            }
        }
    }
    #pragma unroll
    for (int a = 0; a < 2; a++) {
        float pb[4] = {0.f, 0.f, 0.f, 0.f};
        #pragma unroll
        for (int ct = 0; ct < 8; ct++) {
            const float mv = smean[ct * 16 + cl];
            #pragma unroll
            for (int r = 0; r < 4; r++) {
                const float wv = acc[a][ct][r] * scal;
                Wb[(w * 32 + a * 16 + kq * 4 + r) * 128 + ct * 16 + cl] = (bf16_t)wv;
                pb[r] += wv * mv;
            }
        }
        #pragma unroll
        for (int r = 0; r < 4; r++) {
            float v = pb[r];
            v += __shfl_xor(v, 1);
            v += __shfl_xor(v, 2);
            v += __shfl_xor(v, 4);
            v += __shfl_xor(v, 8);
            if (cl == 0) bias[w * 32 + a * 16 + kq * 4 + r] = v;
        }
    }
}

// ============ Kernel 4: out = X * W^T - bias (bf16 MFMA, split-X) ===========
// UNCHANGED from round 11 (verified): grid-stride, W staged once, X register
// double-buffer, swapped-operand MFMA, f32x4 nontemporal stores.
__global__ __launch_bounds__(256, 4) void k_out(const float* __restrict__ X,
        const bf16_t* __restrict__ Wb, const float* __restrict__ bias,
        float* __restrict__ out) {
    __shared__ bf16_t sW[128][136];
    __shared__ float sBias[128];
    const int t = threadIdx.x;
    const int w = t >> 6, lane = t & 63;
    const int cl = lane & 15, kq = lane >> 4;
    const int G = gridDim.x;

    float4 A0[8], A1[8];

    auto GLOAD = [&](int tl, float4 (&B)[8]) {
        const size_t rowb = (size_t)tl * 64 + (size_t)w * 16;
        const bool v = rowb < NROWS;          // wave-uniform (NROWS%16==0)
        const float* xr = X + (rowb + cl) * 128;
        #pragma unroll
        for (int kb = 0; kb < 4; kb++) {
            B[2*kb]   = v ? *reinterpret_cast<const float4*>(xr + kb*32 + kq*8)
                          : float4{0.f,0.f,0.f,0.f};
            B[2*kb+1] = v ? *reinterpret_cast<const float4*>(xr + kb*32 + kq*8 + 4)
                          : float4{0.f,0.f,0.f,0.f};
        }
    };
    auto COMPSTORE = [&](int tl, const float4 (&B)[8]) {
        const size_t rowbase = (size_t)tl * 64 + (size_t)w * 16;
        if (rowbase >= NROWS) return;         // no barriers in loop: safe
        bf16x8 xh[4], xl[4];
        #pragma unroll
        for (int kb = 0; kb < 4; kb++) {
            const float4 v0 = B[2*kb], v1 = B[2*kb+1];
            const float xv[8] = {v0.x, v0.y, v0.z, v0.w, v1.x, v1.y, v1.z, v1.w};
            bf16x8 h, l;
            #pragma unroll
            for (int j = 0; j < 8; j++) {
                h[j] = (bf16_t)xv[j];
                l[j] = (bf16_t)(xv[j] - (float)h[j]);
            }
            xh[kb] = h; xl[kb] = l;
        }
        float* orow = out + (rowbase + cl) * 128;
        #pragma unroll
        for (int ct = 0; ct < 8; ct++) {
            f32x4 acc = (f32x4){0.f, 0.f, 0.f, 0.f};
            const int d = ct * 16 + cl;
            #pragma unroll
            for (int kb = 0; kb < 4; kb++) {
                const bf16x8 wf = *reinterpret_cast<const bf16x8*>(&sW[d][kb*32 + kq*8]);
                acc = __builtin_amdgcn_mfma_f32_16x16x32_bf16(wf, xl[kb], acc, 0, 0, 0);
                acc = __builtin_amdgcn_mfma_f32_16x16x32_bf16(wf, xh[kb], acc, 0, 0, 0);
            }
            const f32x4 bv = *reinterpret_cast<const f32x4*>(&sBias[ct * 16 + kq * 4]);
            const f32x4 o = acc - bv;
            __builtin_nontemporal_store(o,
                reinterpret_cast<f32x4*>(&orow[ct * 16 + kq * 4]));
        }
    };

    int t0 = blockIdx.x;                      // G=1024 < NCHK: all blocks work
    GLOAD(t0, A0);                            // issue X before W staging
    #pragma unroll
    for (int i = 0; i < 8; i++) {             // W staging: 8 x 16B per thread
        const int idx = (t + (i << 8)) << 3;
        *reinterpret_cast<bf16x8*>(&sW[idx >> 7][idx & 127]) =
            *reinterpret_cast<const bf16x8*>(&Wb[idx]);
    }
    if (t < 128) sBias[t] = bias[t];
    __syncthreads();
    for (;;) {
        const int t1 = t0 + G;
        if (t1 < NCHK) GLOAD(t1, A1);         // prefetch next while computing
        COMPSTORE(t0, A0);
        if (t1 >= NCHK) break;
        const int t2 = t1 + G;
        if (t2 < NCHK) GLOAD(t2, A0);
        COMPSTORE(t1, A1);
        if (t2 >= NCHK) break;
        t0 = t2;
    }
}

extern "C" void kernel_launch(void* const* d_in, const int* in_sizes, int n_in,
                              void* d_out, int out_size, void* d_ws, size_t ws_size,
                              hipStream_t stream) {
    const float* X = (const float*)d_in[0];
    const float* R = (const float*)d_in[1];   // running_rot[0], row-major [d][c]
    float* out = (float*)d_out;
    char* ws = (char*)d_ws;
    float*  gramTot = (float*)(ws + GT_OFF);
    bf16_t* Wb      = (bf16_t*)(ws + WB_OFF);
    float*  bias    = (float*)(ws + BIAS_OFF);
    float*  csPart  = (float*)(ws + CS_OFF);
    float*  csPart2 = (float*)(ws + CS2_OFF);

    int G = 512;
    size_t avail = (ws_size > GRAM_OFF) ? (ws_size - GRAM_OFF) : 0;
    if (avail < (size_t)G * 65536) {
        G = (int)(avail / 65536);
        if (G < 1) G = 1;
        if (G > 512) G = 512;
    }
    float* gramPart = (float*)(ws + GRAM_OFF);

    k_stats<<<dim3(G), dim3(256), 0, stream>>>(X, csPart, gramPart);
    k_gred<<<dim3(264), dim3(256), 0, stream>>>(gramPart, csPart, gramTot, csPart2, G);
    k_ns<<<dim3(1), dim3(256), 0, stream>>>(gramTot, csPart2, R, Wb, bias);
    k_out<<<dim3(1024), dim3(256), 0, stream>>>(X, Wb, bias, out);
}

// Round 13
// 198.118 us; speedup vs baseline: 1.0304x; 1.0304x over previous
//
#include <hip/hip_runtime.h>
#include <math.h>

#define NROWS  500000
#define NCHK   7813      // ceil(500000/64)
#define EPSV   1e-5f

typedef __bf16 bf16_t;
typedef __bf16 bf16x4 __attribute__((ext_vector_type(4)));
typedef __bf16 bf16x8 __attribute__((ext_vector_type(8)));
typedef float  f32x4  __attribute__((ext_vector_type(4)));

// ---- ws layout (byte offsets) ----
static const size_t GT_OFF   = 131072;   // gramTot 16384 f32 (64KB)
static const size_t WB_OFF   = 327680;   // W bf16 (32KB)
static const size_t BIAS_OFF = 360960;   // 128 f32
static const size_t CS_OFF   = 393216;   // colsum partials G*128 f32 (ends 655360)
static const size_t CS2_OFF  = 786432;   // colsum slice partials 8*128 f32
static const size_t GRAM_OFF = 1048576;  // gram partials G*16384 f32

// ============ Kernel 1: column sums + Gram partials (bf16 MFMA) =============
// EXACT round-11 body (1-deep pipeline; round-12's 2-deep pushed VGPR past the
// 128 occupancy step -> 2 waves/SIMD, regressed a BW-bound kernel). Epilogue:
// transposed contiguous f32x4 nt stores (Gram^T == Gram).
__global__ __launch_bounds__(256) void k_stats(const float* __restrict__ X,
        float* __restrict__ csPart, float* __restrict__ gramPart) {
    __shared__ bf16_t sxtT[2][8192];    // [buf][f-major 128x64 swizzled] 32KB
    __shared__ float  scs[256][4];
    const int t    = threadIdx.x;
    const int lane = t & 63;
    const int w    = t >> 6;     // wave 0..3
    const int oct  = t >> 5;     // sample octet 0..7
    const int fg4  = t & 31;     // feature quad 0..31
    const int cl   = lane & 15;
    const int kq   = lane >> 4;
    const int G    = gridDim.x;

    f32x4 acc[2][8];
    #pragma unroll
    for (int a = 0; a < 2; a++)
        #pragma unroll
        for (int b = 0; b < 8; b++)
            acc[a][b] = (f32x4){0.f, 0.f, 0.f, 0.f};
    float cs0 = 0.f, cs1 = 0.f, cs2 = 0.f, cs3 = 0.f;

    f32x4 R[8];

    auto KF = [](int f) { return (f ^ (f >> 3)) & 7; };

    auto GLOADC = [&](int ch) {
        const size_t row0 = (size_t)ch << 6;
        #pragma unroll
        for (int i = 0; i < 8; i++) {
            const size_t row = row0 + oct * 8 + i;
            R[i] = (row < NROWS)
                 ? *reinterpret_cast<const f32x4*>(X + row * 128 + fg4 * 4)
                 : (f32x4){0.f, 0.f, 0.f, 0.f};
        }
    };
    auto DSWRITEC = [&](int buf) {
        #pragma unroll
        for (int i = 0; i < 8; i++) {
            cs0 += R[i][0]; cs1 += R[i][1]; cs2 += R[i][2]; cs3 += R[i][3];
        }
        bf16_t* S = sxtT[buf];
        #pragma unroll
        for (int j = 0; j < 4; j++) {
            const int f = fg4 * 4 + j;
            const int g = oct ^ KF(f);
            bf16x8 v;
            #pragma unroll
            for (int i = 0; i < 8; i++) v[i] = (bf16_t)R[i][j];
            *reinterpret_cast<bf16x8*>(&S[f * 64 + g * 8]) = v;
        }
    };
    auto MFMAC = [&](int buf) {
        const bf16_t* S = sxtT[buf];
        #pragma unroll
        for (int kb = 0; kb < 2; kb++) {
            const int gq = kb * 4 + kq;            // sample-group index
            bf16x8 fa[2];
            #pragma unroll
            for (int a = 0; a < 2; a++) {
                const int f = (w * 2 + a) * 16 + cl;
                fa[a] = *reinterpret_cast<const bf16x8*>(&S[f * 64 + ((gq ^ KF(f)) << 3)]);
            }
            #pragma unroll
            for (int b = 0; b < 8; b++) {
                const int f = b * 16 + cl;
                const bf16x8 fb = *reinterpret_cast<const bf16x8*>(&S[f * 64 + ((gq ^ KF(f)) << 3)]);
                acc[0][b] = __builtin_amdgcn_mfma_f32_16x16x32_bf16(fa[0], fb, acc[0][b], 0, 0, 0);
                acc[1][b] = __builtin_amdgcn_mfma_f32_16x16x32_bf16(fa[1], fb, acc[1][b], 0, 0, 0);
            }
        }
    };

    int ch0 = blockIdx.x;
    GLOADC(ch0);
    DSWRITEC(0);
    __syncthreads();
    for (;;) {
        const int ch1 = ch0 + G;
        const bool v1 = ch1 < NCHK;
        if (v1) GLOADC(ch1);
        MFMAC(0);
        if (v1) DSWRITEC(1);
        __syncthreads();
        if (!v1) break;
        const int ch2 = ch1 + G;
        const bool v2 = ch2 < NCHK;
        if (v2) GLOADC(ch2);
        MFMAC(1);
        if (v2) DSWRITEC(0);
        __syncthreads();
        if (!v2) break;
        ch0 = ch2;
    }

    // Epilogue: transposed contiguous f32x4 nt stores (Gram^T == Gram).
    float* gp = gramPart + (size_t)blockIdx.x * 16384;
    #pragma unroll
    for (int a = 0; a < 2; a++)
        #pragma unroll
        for (int b = 0; b < 8; b++) {
            const int col  = b * 16 + cl;
            const int row0 = (w * 2 + a) * 16 + kq * 4;
            __builtin_nontemporal_store(acc[a][b],
                reinterpret_cast<f32x4*>(&gp[col * 128 + row0]));
        }
    scs[t][0] = cs0; scs[t][1] = cs1; scs[t][2] = cs2; scs[t][3] = cs3;
    __syncthreads();
    if (t < 128) {
        float s = 0.f;
        #pragma unroll
        for (int q = 0; q < 8; q++) s += scs[q * 32 + (t >> 2)][t & 3];
        csPart[(size_t)blockIdx.x * 128 + t] = s;
    }
}

// ============ Kernel 2: coalesced reduction -> gramTot + colsum slices ======
// Round-12 version (kept): blocks 0..255 gram; 256..263 colsum slices (8
// latency-bound iters each vs the old single mean block's 64).
__global__ __launch_bounds__(256) void k_gred(const float* __restrict__ gramPart,
        const float* __restrict__ csPart, float* __restrict__ gramTot,
        float* __restrict__ csPart2, int G) {
    const int t = threadIdx.x;
    const int b = blockIdx.x;
    if (b >= 256) {                       // ---- colsum slice ----
        const int s = b - 256;
        if (t < 128) {
            float sum = 0.f;
            int g = s;
            for (; g + 56 < G; g += 64) {
                float p[8];
                #pragma unroll
                for (int u = 0; u < 8; u++)
                    p[u] = csPart[(size_t)(g + 8 * u) * 128 + t];
                sum += ((p[0] + p[1]) + (p[2] + p[3])) + ((p[4] + p[5]) + (p[6] + p[7]));
            }
            for (; g < G; g += 8) sum += csPart[(size_t)g * 128 + t];
            csPart2[s * 128 + t] = sum;
        }
        return;
    }
    const int e  = b * 64 + (t & 63);
    const int sl = t >> 6;                // g-slice 0..3
    float s = 0.f;
    int g = sl;
    for (; g + 28 < G; g += 32) {         // 8 loads of stride-4 per iter
        float v[8];
        #pragma unroll
        for (int u = 0; u < 8; u++)
            v[u] = __builtin_nontemporal_load(&gramPart[(size_t)(g + 4 * u) * 16384 + e]);
        s += ((v[0] + v[1]) + (v[2] + v[3])) + ((v[4] + v[5]) + (v[6] + v[7]));
    }
    for (; g < G; g += 4)
        s += __builtin_nontemporal_load(&gramPart[(size_t)g * 16384 + e]);
    __shared__ float red[4][64];
    red[sl][t & 63] = s;
    __syncthreads();
    if (t < 64)
        gramTot[b * 64 + t] = (red[0][t] + red[1][t]) + (red[2][t] + red[3][t]);
}

// ============ Kernel 3: fused Sigma->Sn, Newton-Schulz x5, W, bias ==========
// Round-12 version (kept): smean folded from 8 colsum slices (1KB read).
__global__ __launch_bounds__(256) void k_ns(const float* __restrict__ gramTot,
        const float* __restrict__ csPart2, const float* __restrict__ Rg,
        bf16_t* __restrict__ Wb, float* __restrict__ bias) {
    __shared__ bf16_t sPh[16384], sPl[16384], sSn[16384], sTT[16384];
    __shared__ float smean[128];
    const int t = threadIdx.x;
    const int w = t >> 6, lane = t & 63;
    const int cl = lane & 15, kq = lane >> 4;

    if (t < 128) {
        float m = 0.f;
        #pragma unroll
        for (int s = 0; s < 8; s++) m += csPart2[s * 128 + t];
        smean[t] = m * (1.0f / (float)NROWS);
    }
    __syncthreads();

    float* rs = reinterpret_cast<float*>(sTT);
    float dv = 0.f;
    if (t < 128) {
        const float m = smean[t];
        dv = gramTot[t * 129] * (1.0f / (float)NROWS) - m * m + EPSV;
    }
    rs[t] = dv;
    __syncthreads();
    #pragma unroll
    for (int off = 128; off > 0; off >>= 1) {
        if (t < off) rs[t] += rs[t + off];
        __syncthreads();
    }
    const float rTr = 1.0f / rs[0];
    __syncthreads();
    for (int i = 0; i < 64; i++) {
        const int e = t + (i << 8);
        const int r = e >> 7, c = e & 127;
        float s = gramTot[e] * (1.0f / (float)NROWS) - smean[r] * smean[c];
        if (r == c) s += EPSV;
        const int ix = r * 128 + (c ^ ((r & 7) << 3));
        const float snv = s * rTr;
        sSn[ix] = (bf16_t)snv;
        const float p0 = ((r == c) ? 1.5f : 0.f) - 0.5f * snv;
        const bf16_t ph = (bf16_t)p0;
        sPh[ix] = ph;
        sPl[ix] = (bf16_t)(p0 - (float)ph);
    }
    __syncthreads();

    f32x4 acc[2][8];
    auto NSMM = [&](const bf16_t* __restrict__ Bm) {
        #pragma unroll
        for (int a = 0; a < 2; a++)
            #pragma unroll
            for (int ct = 0; ct < 8; ct++) acc[a][ct] = (f32x4){0.f, 0.f, 0.f, 0.f};
        #pragma unroll
        for (int kb = 0; kb < 4; kb++) {
            const int k0 = kb * 32 + kq * 8;
            bf16x8 ah[2], al[2];
            #pragma unroll
            for (int a = 0; a < 2; a++) {
                const int ra = w * 32 + a * 16 + cl;
                const int ia = ra * 128 + (k0 ^ ((ra & 7) << 3));
                ah[a] = *reinterpret_cast<const bf16x8*>(&sPh[ia]);
                al[a] = *reinterpret_cast<const bf16x8*>(&sPl[ia]);
            }
            #pragma unroll
            for (int ct = 0; ct < 8; ct++) {
                const int rb = ct * 16 + cl;
                const bf16x8 bb = *reinterpret_cast<const bf16x8*>(
                    &Bm[rb * 128 + (k0 ^ ((rb & 7) << 3))]);
                acc[0][ct] = __builtin_amdgcn_mfma_f32_16x16x32_bf16(ah[0], bb, acc[0][ct], 0, 0, 0);
                acc[0][ct] = __builtin_amdgcn_mfma_f32_16x16x32_bf16(al[0], bb, acc[0][ct], 0, 0, 0);
                acc[1][ct] = __builtin_amdgcn_mfma_f32_16x16x32_bf16(ah[1], bb, acc[1][ct], 0, 0, 0);
                acc[1][ct] = __builtin_amdgcn_mfma_f32_16x16x32_bf16(al[1], bb, acc[1][ct], 0, 0, 0);
            }
        }
    };
    auto WRT = [&](bf16_t* __restrict__ D) {
        #pragma unroll
        for (int a = 0; a < 2; a++) {
            const int ro0 = w * 32 + a * 16 + kq * 4;
            #pragma unroll
            for (int ct = 0; ct < 8; ct++) {
                const int co = ct * 16 + cl;
                bf16x4 v = { (bf16_t)acc[a][ct][0], (bf16_t)acc[a][ct][1],
                             (bf16_t)acc[a][ct][2], (bf16_t)acc[a][ct][3] };
                *reinterpret_cast<bf16x4*>(&D[co * 128 + (ro0 ^ ((co & 7) << 3))]) = v;
            }
        }
    };

    for (int it = 0; it < 4; it++) {
        NSMM(sSn);
        WRT(sTT);
        __syncthreads();
        NSMM(sTT);
        __syncthreads();
        WRT(sTT);
        __syncthreads();
        NSMM(sTT);
        #pragma unroll
        for (int a = 0; a < 2; a++) {
            const int ro0 = w * 32 + a * 16 + kq * 4;
            #pragma unroll
            for (int ct = 0; ct < 8; ct++) {
                const int co = ct * 16 + cl;
                const int ix = co * 128 + (ro0 ^ ((co & 7) << 3));
                bf16x4 ph4 = *reinterpret_cast<const bf16x4*>(&sPh[ix]);
                bf16x4 pl4 = *reinterpret_cast<const bf16x4*>(&sPl[ix]);
                bf16x4 nh, nl;
                #pragma unroll
                for (int r = 0; r < 4; r++) {
                    const float pold = (float)ph4[r] + (float)pl4[r];
                    const float pn = 1.5f * pold - 0.5f * acc[a][ct][r];
                    nh[r] = (bf16_t)pn;
                    nl[r] = (bf16_t)(pn - (float)nh[r]);
                }
                *reinterpret_cast<bf16x4*>(&sPh[ix]) = nh;
                *reinterpret_cast<bf16x4*>(&sPl[ix]) = nl;
            }
        }
        __syncthreads();
    }

    const float scal = sqrtf(rTr);
    #pragma unroll
    for (int a = 0; a < 2; a++)
        #pragma unroll
        for (int ct = 0; ct < 8; ct++) acc[a][ct] = (f32x4){0.f, 0.f, 0.f, 0.f};
    #pragma unroll
    for (int kb = 0; kb < 4; kb++) {
        const int k0 = kb * 32 + kq * 8;
        bf16x8 ah[2], al[2];
        #pragma unroll
        for (int a = 0; a < 2; a++) {
            const int ra = w * 32 + a * 16 + cl;
            const float4 rv0 = *reinterpret_cast<const float4*>(&Rg[ra * 128 + k0]);
            const float4 rv1 = *reinterpret_cast<const float4*>(&Rg[ra * 128 + k0 + 4]);
            const float rv[8] = {rv0.x, rv0.y, rv0.z, rv0.w, rv1.x, rv1.y, rv1.z, rv1.w};
            bf16x8 h, l;
            #pragma unroll
            for (int j = 0; j < 8; j++) {
                h[j] = (bf16_t)rv[j];
                l[j] = (bf16_t)(rv[j] - (float)h[j]);
            }
            ah[a] = h; al[a] = l;
        }
        #pragma unroll
        for (int ct = 0; ct < 8; ct++) {
            const int rb = ct * 16 + cl;
            const int ib = rb * 128 + (k0 ^ ((rb & 7) << 3));
            const bf16x8 bh = *reinterpret_cast<const bf16x8*>(&sPh[ib]);
            const bf16x8 bl = *reinterpret_cast<const bf16x8*>(&sPl[ib]);
            #pragma unroll
            for (int a = 0; a < 2; a++) {
                acc[a][ct] = __builtin_amdgcn_mfma_f32_16x16x32_bf16(ah[a], bh, acc[a][ct], 0, 0, 0);
                acc[a][ct] = __builtin_amdgcn_mfma_f32_16x16x32_bf16(al[a], bh, acc[a][ct], 0, 0, 0);
                acc[a][ct] = __builtin_amdgcn_mfma_f32_16x16x32_bf16(ah[a], bl, acc[a][ct], 0, 0, 0);
            }
        }
    }
    #pragma unroll
    for (int a = 0; a < 2; a++) {
        float pb[4] = {0.f, 0.f, 0.f, 0.f};
        #pragma unroll
        for (int ct = 0; ct < 8; ct++) {
            const float mv = smean[ct * 16 + cl];
            #pragma unroll
            for (int r = 0; r < 4; r++) {
                const float wv = acc[a][ct][r] * scal;
                Wb[(w * 32 + a * 16 + kq * 4 + r) * 128 + ct * 16 + cl] = (bf16_t)wv;
                pb[r] += wv * mv;
            }
        }
        #pragma unroll
        for (int r = 0; r < 4; r++) {
            float v = pb[r];
            v += __shfl_xor(v, 1);
            v += __shfl_xor(v, 2);
            v += __shfl_xor(v, 4);
            v += __shfl_xor(v, 8);
            if (cl == 0) bias[w * 32 + a * 16 + kq * 4 + r] = v;
        }
    }
}

// ============ Kernel 4: out = X * W^T - bias (bf16 MFMA, split-X) ===========
// UNCHANGED from round 11 (verified): grid-stride, W staged once, X register
// double-buffer, swapped-operand MFMA, f32x4 nontemporal stores.
__global__ __launch_bounds__(256, 4) void k_out(const float* __restrict__ X,
        const bf16_t* __restrict__ Wb, const float* __restrict__ bias,
        float* __restrict__ out) {
    __shared__ bf16_t sW[128][136];
    __shared__ float sBias[128];
    const int t = threadIdx.x;
    const int w = t >> 6, lane = t & 63;
    const int cl = lane & 15, kq = lane >> 4;
    const int G = gridDim.x;

    float4 A0[8], A1[8];

    auto GLOAD = [&](int tl, float4 (&B)[8]) {
        const size_t rowb = (size_t)tl * 64 + (size_t)w * 16;
        const bool v = rowb < NROWS;          // wave-uniform (NROWS%16==0)
        const float* xr = X + (rowb + cl) * 128;
        #pragma unroll
        for (int kb = 0; kb < 4; kb++) {
            B[2*kb]   = v ? *reinterpret_cast<const float4*>(xr + kb*32 + kq*8)
                          : float4{0.f,0.f,0.f,0.f};
            B[2*kb+1] = v ? *reinterpret_cast<const float4*>(xr + kb*32 + kq*8 + 4)
                          : float4{0.f,0.f,0.f,0.f};
        }
    };
    auto COMPSTORE = [&](int tl, const float4 (&B)[8]) {
        const size_t rowbase = (size_t)tl * 64 + (size_t)w * 16;
        if (rowbase >= NROWS) return;         // no barriers in loop: safe
        bf16x8 xh[4], xl[4];
        #pragma unroll
        for (int kb = 0; kb < 4; kb++) {
            const float4 v0 = B[2*kb], v1 = B[2*kb+1];
            const float xv[8] = {v0.x, v0.y, v0.z, v0.w, v1.x, v1.y, v1.z, v1.w};
            bf16x8 h, l;
            #pragma unroll
            for (int j = 0; j < 8; j++) {
                h[j] = (bf16_t)xv[j];
                l[j] = (bf16_t)(xv[j] - (float)h[j]);
            }
            xh[kb] = h; xl[kb] = l;
        }
        float* orow = out + (rowbase + cl) * 128;
        #pragma unroll
        for (int ct = 0; ct < 8; ct++) {
            f32x4 acc = (f32x4){0.f, 0.f, 0.f, 0.f};
            const int d = ct * 16 + cl;
            #pragma unroll
            for (int kb = 0; kb < 4; kb++) {
                const bf16x8 wf = *reinterpret_cast<const bf16x8*>(&sW[d][kb*32 + kq*8]);
                acc = __builtin_amdgcn_mfma_f32_16x16x32_bf16(wf, xl[kb], acc, 0, 0, 0);
                acc = __builtin_amdgcn_mfma_f32_16x16x32_bf16(wf, xh[kb], acc, 0, 0, 0);
            }
            const f32x4 bv = *reinterpret_cast<const f32x4*>(&sBias[ct * 16 + kq * 4]);
            const f32x4 o = acc - bv;
            __builtin_nontemporal_store(o,
                reinterpret_cast<f32x4*>(&orow[ct * 16 + kq * 4]));
        }
    };

    int t0 = blockIdx.x;                      // G=1024 < NCHK: all blocks work
    GLOAD(t0, A0);                            // issue X before W staging
    #pragma unroll
    for (int i = 0; i < 8; i++) {             // W staging: 8 x 16B per thread
        const int idx = (t + (i << 8)) << 3;
        *reinterpret_cast<bf16x8*>(&sW[idx >> 7][idx & 127]) =
            *reinterpret_cast<const bf16x8*>(&Wb[idx]);
    }
    if (t < 128) sBias[t] = bias[t];
    __syncthreads();
    for (;;) {
        const int t1 = t0 + G;
        if (t1 < NCHK) GLOAD(t1, A1);         // prefetch next while computing
        COMPSTORE(t0, A0);
        if (t1 >= NCHK) break;
        const int t2 = t1 + G;
        if (t2 < NCHK) GLOAD(t2, A0);
        COMPSTORE(t1, A1);
        if (t2 >= NCHK) break;
        t0 = t2;
    }
}

extern "C" void kernel_launch(void* const* d_in, const int* in_sizes, int n_in,
                              void* d_out, int out_size, void* d_ws, size_t ws_size,
                              hipStream_t stream) {
    const float* X = (const float*)d_in[0];
    const float* R = (const float*)d_in[1];   // running_rot[0], row-major [d][c]
    float* out = (float*)d_out;
    char* ws = (char*)d_ws;
    float*  gramTot = (float*)(ws + GT_OFF);
    bf16_t* Wb      = (bf16_t*)(ws + WB_OFF);
    float*  bias    = (float*)(ws + BIAS_OFF);
    float*  csPart  = (float*)(ws + CS_OFF);
    float*  csPart2 = (float*)(ws + CS2_OFF);

    int G = 512;
    size_t avail = (ws_size > GRAM_OFF) ? (ws_size - GRAM_OFF) : 0;
    if (avail < (size_t)G * 65536) {
        G = (int)(avail / 65536);
        if (G < 1) G = 1;
        if (G > 512) G = 512;
    }
    float* gramPart = (float*)(ws + GRAM_OFF);

    k_stats<<<dim3(G), dim3(256), 0, stream>>>(X, csPart, gramPart);
    k_gred<<<dim3(264), dim3(256), 0, stream>>>(gramPart, csPart, gramTot, csPart2, G);
    k_ns<<<dim3(1), dim3(256), 0, stream>>>(gramTot, csPart2, R, Wb, bias);
    k_out<<<dim3(1024), dim3(256), 0, stream>>>(X, Wb, bias, out);
}